// Round 1
// baseline (275.448 us; speedup 1.0000x reference)
//
#include <hip/hip_runtime.h>
#include <math.h>

#define ALPHA 0.12f
#define BETA  0.88f
#define OMEGA 6.0f
#define TWO_PI 6.28318530717958647692f

constexpr int Bn   = 4;
constexpr int Tn   = 4096;
constexpr int Dn   = 2048;
constexpr int HALF = Dn / 2;      // 1024
constexpr int L    = 64;          // chunk length
constexpr int NC   = Tn / L;      // 64 chunks

constexpr float beta_pow(int n) {
    float r = 1.0f;
    for (int i = 0; i < n; ++i) r *= BETA;
    return r;
}
constexpr float BETA_L = beta_pow(L);

// ---------------------------------------------------------------------------
// Kernel 0: theta table. theta_t = (OMEGA*log1p(t+1+step_idx)) mod 2pi
// ---------------------------------------------------------------------------
__global__ void k_theta(float* __restrict__ ctab, float* __restrict__ stab,
                        const int* __restrict__ step_idx) {
    int t = blockIdx.x * blockDim.x + threadIdx.x;
    if (t >= Tn) return;
    float tg = (float)(t + 1 + *step_idx);
    float theta = fmodf(OMEGA * log1pf(tg), TWO_PI);
    ctab[t] = cosf(theta);
    stab[t] = sinf(theta);
}

// ---------------------------------------------------------------------------
// Kernel 1: per-chunk local scan endpoint (zero init).
// S[b, c, d] = sum_{i=0..L-1} BETA^(L-1-i) * u[b, c*L+i, d]
// One thread per (b, c, d). Coalesced over d.
// ---------------------------------------------------------------------------
__global__ void k_chunksum(const float* __restrict__ x,
                           const float* __restrict__ input_scale,
                           float* __restrict__ S) {
    int gid = blockIdx.x * blockDim.x + threadIdx.x;     // 2^19 threads
    int d = gid & (Dn - 1);
    int c = (gid >> 11) & (NC - 1);
    int b = gid >> 17;
    const float sc = ALPHA * (*input_scale);
    const float* xp = x + ((size_t)b * Tn + (size_t)c * L) * Dn + d;
    float m = 0.0f;
#pragma unroll 8
    for (int i = 0; i < L; ++i) {
        m = BETA * m + sc * xp[(size_t)i * Dn];
    }
    S[gid] = m;
}

// ---------------------------------------------------------------------------
// Kernel 2: sequential combine over chunks, in place.
// On entry SC[b,c,d] = S (local sums); on exit SC[b,c,d] = carry-in m for
// chunk c (the reference m at t = c*L - 1, i.e. m before the chunk starts).
// One thread per (b, d).
// ---------------------------------------------------------------------------
__global__ void k_carry(float* __restrict__ SC,
                        const float* __restrict__ mem_state) {
    int gid = blockIdx.x * blockDim.x + threadIdx.x;     // 8192 threads
    int d = gid & (Dn - 1);
    int b = gid >> 11;
    float m = mem_state[d];                              // broadcast over b
    for (int c = 0; c < NC; ++c) {
        size_t idx = ((size_t)(b * NC + c) * Dn) + d;
        float s = SC[idx];
        SC[idx] = m;                                     // carry-in for chunk c
        m = BETA_L * m + s;                              // m at end of chunk c
    }
}

// ---------------------------------------------------------------------------
// Kernel 3: final pass. Re-run the exact sequential recurrence from the
// chunk carry-in, apply the rotation on the (d, d+HALF) pair, residual add.
// One thread per (b, c, pair p in [0,HALF)). Coalesced over p.
// ---------------------------------------------------------------------------
__global__ void k_final(const float* __restrict__ x,
                        const float* __restrict__ gate,
                        const float* __restrict__ input_scale,
                        const float* __restrict__ ctab,
                        const float* __restrict__ stab,
                        const float* __restrict__ C,
                        float* __restrict__ out) {
    int gid = blockIdx.x * blockDim.x + threadIdx.x;     // 2^18 threads
    int p = gid & (HALF - 1);
    int c = (gid >> 10) & (NC - 1);
    int b = gid >> 16;

    const float sc  = ALPHA * (*input_scale);
    const float sig = 1.0f / (1.0f + expf(-(*gate)));

    size_t base = ((size_t)b * Tn + (size_t)c * L) * Dn;
    const float* xa = x + base + p;
    const float* xb = x + base + p + HALF;
    float* oa = out + base + p;
    float* ob = out + base + p + HALF;

    size_t cbase = (size_t)(b * NC + c) * Dn;
    float ma = C[cbase + p];
    float mb = C[cbase + p + HALF];

    int t0 = c * L;
#pragma unroll 4
    for (int i = 0; i < L; ++i) {
        float va = xa[(size_t)i * Dn];
        float vb = xb[(size_t)i * Dn];
        ma = BETA * ma + sc * va;
        mb = BETA * mb + sc * vb;
        float cth = ctab[t0 + i];
        float sth = stab[t0 + i];
        oa[(size_t)i * Dn] = va + sig * (ma * cth - mb * sth);
        ob[(size_t)i * Dn] = vb + sig * (ma * sth + mb * cth);
    }
}

// ---------------------------------------------------------------------------
extern "C" void kernel_launch(void* const* d_in, const int* in_sizes, int n_in,
                              void* d_out, int out_size, void* d_ws, size_t ws_size,
                              hipStream_t stream) {
    const float* x           = (const float*)d_in[0];
    const float* gate        = (const float*)d_in[1];
    const float* input_scale = (const float*)d_in[2];
    const float* mem_state   = (const float*)d_in[3];
    const int*   step_idx    = (const int*)d_in[4];
    float* out = (float*)d_out;

    float* ws   = (float*)d_ws;
    float* ctab = ws;             // Tn floats
    float* stab = ws + Tn;        // Tn floats
    float* SC   = ws + 2 * Tn;    // Bn*NC*Dn floats (~2 MiB)

    k_theta<<<Tn / 256, 256, 0, stream>>>(ctab, stab, step_idx);
    k_chunksum<<<(Bn * NC * Dn) / 256, 256, 0, stream>>>(x, input_scale, SC);
    k_carry<<<(Bn * Dn) / 256, 256, 0, stream>>>(SC, mem_state);
    k_final<<<(Bn * NC * HALF) / 256, 256, 0, stream>>>(x, gate, input_scale,
                                                        ctab, stab, SC, out);
}

// Round 3
// 259.411 us; speedup vs baseline: 1.0618x; 1.0618x over previous
//
#include <hip/hip_runtime.h>
#include <math.h>

#define ALPHA 0.12f
#define BETA  0.88f
#define OMEGA 6.0f
#define TWO_PI 6.28318530717958647692f

constexpr int Bn   = 4;
constexpr int Tn   = 4096;
constexpr int Dn   = 2048;
constexpr int HALF = Dn / 2;      // 1024
constexpr int L    = 64;          // chunk length
constexpr int NC   = Tn / L;      // 64 chunks

typedef float fx4 __attribute__((ext_vector_type(4)));

constexpr float beta_pow(int n) {
    float r = 1.0f;
    for (int i = 0; i < n; ++i) r *= BETA;
    return r;
}
constexpr float BETA_L = beta_pow(L);

// ---------------------------------------------------------------------------
// Kernel 1: per-chunk local scan endpoint (zero init), fx4 lanes.
// S[b, c, d] = sum_{i=0..L-1} BETA^(L-1-i) * u[b, c*L+i, d]
// One thread per (b, c, d4). 131072 threads = 512 blocks.
// ---------------------------------------------------------------------------
__global__ void k_chunksum(const float* __restrict__ x,
                           const float* __restrict__ input_scale,
                           float* __restrict__ S) {
    int gid = blockIdx.x * blockDim.x + threadIdx.x;
    int d4 = gid & (Dn / 4 - 1);          // 0..511
    int c  = (gid >> 9) & (NC - 1);       // 0..63
    int b  = gid >> 15;                   // 0..3
    const float sc = ALPHA * (*input_scale);

    const fx4* xp = (const fx4*)(x + ((size_t)b * Tn + (size_t)c * L) * Dn) + d4;
    fx4 m = (fx4)(0.0f);
#pragma unroll 8
    for (int i = 0; i < L; ++i) {
        fx4 v = xp[(size_t)i * (Dn / 4)];
        m = BETA * m + sc * v;
    }
    ((fx4*)S)[gid] = m;   // gid*4 == b*NC*Dn + c*Dn + d4*4
}

// ---------------------------------------------------------------------------
// Kernel 2 (fused): blocks [0,8): sequential carry combine over chunks
// (fx4 lanes, in place); blocks [8,24): theta cos/sin table.
// ---------------------------------------------------------------------------
__global__ void k_mid(float* __restrict__ SC,
                      const float* __restrict__ mem_state,
                      float* __restrict__ ctab, float* __restrict__ stab,
                      const int* __restrict__ step_idx) {
    if (blockIdx.x < 8) {
        int gid = blockIdx.x * blockDim.x + threadIdx.x;  // 0..2047
        int d4 = gid & (Dn / 4 - 1);
        int b  = gid >> 9;
        fx4 m = ((const fx4*)mem_state)[d4];
        fx4* scp = (fx4*)SC;
        for (int c = 0; c < NC; ++c) {
            int idx = (b * NC + c) * (Dn / 4) + d4;
            fx4 s = scp[idx];
            scp[idx] = m;                                 // carry-in for chunk c
            m = BETA_L * m + s;
        }
    } else {
        int t = (blockIdx.x - 8) * blockDim.x + threadIdx.x;  // 0..4095
        float tg = (float)(t + 1 + *step_idx);
        float theta = fmodf(OMEGA * log1pf(tg), TWO_PI);
        ctab[t] = cosf(theta);
        stab[t] = sinf(theta);
    }
}

// ---------------------------------------------------------------------------
// Kernel 3: final pass, fx4 lanes over pair index p.
// Re-run exact sequential recurrence from chunk carry-in, rotate, residual.
// One thread per (b, c, p4). 65536 threads = 256 blocks.
// Nontemporal stores keep x resident in L3 for this kernel's reads.
// ---------------------------------------------------------------------------
__global__ void k_final(const float* __restrict__ x,
                        const float* __restrict__ gate,
                        const float* __restrict__ input_scale,
                        const float* __restrict__ ctab,
                        const float* __restrict__ stab,
                        const float* __restrict__ C,
                        float* __restrict__ out) {
    int gid = blockIdx.x * blockDim.x + threadIdx.x;
    int p4 = gid & (HALF / 4 - 1);        // 0..255
    int c  = (gid >> 8) & (NC - 1);       // 0..63
    int b  = gid >> 14;                   // 0..3

    const float sc  = ALPHA * (*input_scale);
    const float sig = 1.0f / (1.0f + expf(-(*gate)));

    size_t base = ((size_t)b * Tn + (size_t)c * L) * Dn;
    const fx4* xa = (const fx4*)(x + base) + p4;
    const fx4* xb = (const fx4*)(x + base + HALF) + p4;
    fx4* oa = (fx4*)(out + base) + p4;
    fx4* ob = (fx4*)(out + base + HALF) + p4;

    size_t cbase = (size_t)(b * NC + c) * Dn;
    fx4 ma = ((const fx4*)(C + cbase))[p4];
    fx4 mb = ((const fx4*)(C + cbase + HALF))[p4];

    int t0 = c * L;
#pragma unroll 4
    for (int i = 0; i < L; ++i) {
        fx4 va = xa[(size_t)i * (Dn / 4)];
        fx4 vb = xb[(size_t)i * (Dn / 4)];
        ma = BETA * ma + sc * va;
        mb = BETA * mb + sc * vb;
        float cth = ctab[t0 + i];
        float sth = stab[t0 + i];
        fx4 ra = va + sig * (ma * cth - mb * sth);
        fx4 rb = vb + sig * (ma * sth + mb * cth);
        __builtin_nontemporal_store(ra, &oa[(size_t)i * (Dn / 4)]);
        __builtin_nontemporal_store(rb, &ob[(size_t)i * (Dn / 4)]);
    }
}

// ---------------------------------------------------------------------------
extern "C" void kernel_launch(void* const* d_in, const int* in_sizes, int n_in,
                              void* d_out, int out_size, void* d_ws, size_t ws_size,
                              hipStream_t stream) {
    const float* x           = (const float*)d_in[0];
    const float* gate        = (const float*)d_in[1];
    const float* input_scale = (const float*)d_in[2];
    const float* mem_state   = (const float*)d_in[3];
    const int*   step_idx    = (const int*)d_in[4];
    float* out = (float*)d_out;

    float* ws   = (float*)d_ws;
    float* ctab = ws;             // Tn floats
    float* stab = ws + Tn;        // Tn floats
    float* SC   = ws + 2 * Tn;    // Bn*NC*Dn floats (~2 MiB)

    k_chunksum<<<(Bn * NC * Dn / 4) / 256, 256, 0, stream>>>(x, input_scale, SC);
    k_mid<<<8 + Tn / 256, 256, 0, stream>>>(SC, mem_state, ctab, stab, step_idx);
    k_final<<<(Bn * NC * HALF / 4) / 256, 256, 0, stream>>>(x, gate, input_scale,
                                                            ctab, stab, SC, out);
}